// Round 3
// baseline (371.018 us; speedup 1.0000x reference)
//
#include <hip/hip_runtime.h>

// Embedding gather: out[i, :] = table[indices[i], :]
// VOCAB = 1,000,000 rows x 16 fp32 (64 B/row), NUM_INDICES = 4,194,304.
//
// R1/R2 changes vs R0 (369 us, ~0.9 TB/s effective):
//  - K=8 float4s per thread, phase-pipelined (8 idx loads -> 8 gathers ->
//    8 stores) so each wave keeps ~8 independent VMEM chains in flight
//    instead of one serialized index->gather->store round trip.
//  - Non-temporal stores: the 256 MB write-once output stream must not
//    evict the 64 MB table from L2/L3. Uses a clang ext_vector_type float4
//    because __builtin_nontemporal_store rejects HIP_vector_type.
//  - Stores stay coalesced: thread t writes float4 elements t + j*T,
//    consecutive lanes -> consecutive 16 B.

typedef float vfloat4 __attribute__((ext_vector_type(4)));

#define K_PER_THREAD 8

__global__ void __launch_bounds__(256)
embed_gather_kernel(const int* __restrict__ indices,
                    const vfloat4* __restrict__ table4,
                    vfloat4* __restrict__ out4,
                    long long total4) {
    const long long T = (long long)gridDim.x * blockDim.x;  // total threads
    long long t = (long long)blockIdx.x * blockDim.x + threadIdx.x;

    // Fast path: all K elements in range (true for the exact-division launch).
    long long e_last = t + (long long)(K_PER_THREAD - 1) * T;
    if (e_last < total4) {
        int idx[K_PER_THREAD];
        vfloat4 val[K_PER_THREAD];
        // Phase 1: independent index loads
#pragma unroll
        for (int j = 0; j < K_PER_THREAD; ++j) {
            long long e = t + (long long)j * T;
            idx[j] = indices[e >> 2];
        }
        // Phase 2: independent gathers (each waits only on its own index)
#pragma unroll
        for (int j = 0; j < K_PER_THREAD; ++j) {
            long long e = t + (long long)j * T;
            val[j] = table4[(size_t)idx[j] * 4 + (e & 3)];
        }
        // Phase 3: non-temporal coalesced stores (don't pollute L2/L3)
#pragma unroll
        for (int j = 0; j < K_PER_THREAD; ++j) {
            long long e = t + (long long)j * T;
            __builtin_nontemporal_store(val[j], &out4[e]);
        }
    } else {
        // Tail path (not taken with exact division, kept for safety)
        for (long long e = t; e < total4; e += T) {
            int r = indices[e >> 2];
            vfloat4 v = table4[(size_t)r * 4 + (e & 3)];
            __builtin_nontemporal_store(v, &out4[e]);
        }
    }
}

extern "C" void kernel_launch(void* const* d_in, const int* in_sizes, int n_in,
                              void* d_out, int out_size, void* d_ws, size_t ws_size,
                              hipStream_t stream) {
    const int*     indices = (const int*)d_in[0];
    const vfloat4* table4  = (const vfloat4*)d_in[1];
    vfloat4*       out4    = (vfloat4*)d_out;

    long long total4 = (long long)out_size / 4;           // 16,777,216 float4s
    int block = 256;
    long long threads_needed = (total4 + K_PER_THREAD - 1) / K_PER_THREAD;
    int grid = (int)((threads_needed + block - 1) / block); // 8192 blocks

    embed_gather_kernel<<<grid, block, 0, stream>>>(indices, table4, out4, total4);
}